// Round 1
// baseline (304.998 us; speedup 1.0000x reference)
//
#include <hip/hip_runtime.h>
#include <hip/hip_bf16.h>
#include <math.h>

// Sizes (fixed by the problem)
// N=64 samples, C=512, T=64, P=2016 pairs
// f[n][d][t]: d in [0,256)
// A[i][o][k]: o in [0,32), k = s*64+t in [0,128)
// B[j][k][e] = f[j][s*128+e][t], e in [0,128)
// h1[p][o][e] = sum_k A[i][o][k]*B[j][k][e] + b_c1[o]

// ---------------- K1: conv1d -> Fp (plain) + FT (B-layout) ----------------
__global__ __launch_bounds__(256) void k_conv1d(
    const float* __restrict__ x, const float* __restrict__ w,
    const float* __restrict__ b, float* __restrict__ Fp, float* __restrict__ FT)
{
    int flat = blockIdx.x * 256 + threadIdx.x;   // 262144 total
    int d  = flat & 255;
    int tq = (flat >> 8) & 15;                   // t-quarter: t = tq*4 + [0..4)
    int n  = flat >> 12;
    const float* xp = x + n * 32768 + tq * 4;
    const float* wp = w + d * 512;
    float4 acc = {0.f, 0.f, 0.f, 0.f};
    #pragma unroll 4
    for (int c = 0; c < 512; ++c) {
        float4 xv = *reinterpret_cast<const float4*>(xp + c * 64);
        float wv = wp[c];
        acc.x += wv * xv.x; acc.y += wv * xv.y;
        acc.z += wv * xv.z; acc.w += wv * xv.w;
    }
    float bias = b[d];
    acc.x += bias; acc.y += bias; acc.z += bias; acc.w += bias;
    // plain layout
    *reinterpret_cast<float4*>(Fp + n * 16384 + d * 64 + tq * 4) = acc;
    // B-layout: FT[n][k][e], k = (d>>7)*64 + t, e = d & 127
    int e = d & 127, s = d >> 7;
    float* ftp = FT + n * 16384 + (s * 64 + tq * 4) * 128 + e;
    ftp[0]   = acc.x; ftp[128] = acc.y;
    ftp[256] = acc.z; ftp[384] = acc.w;
}

// ---------------- K_score: per-sample sigmoid(x . w_mlp + b) ----------------
__global__ __launch_bounds__(256) void k_score(
    const float* __restrict__ x, const float* __restrict__ wm,
    const float* __restrict__ bm, float* __restrict__ out)
{
    int n = blockIdx.x;
    const float4* x4 = reinterpret_cast<const float4*>(x + n * 32768);
    const float4* w4 = reinterpret_cast<const float4*>(wm);
    float acc = 0.f;
    for (int u = threadIdx.x; u < 8192; u += 256) {
        float4 a = x4[u], w = w4[u];
        acc += a.x * w.x + a.y * w.y + a.z * w.z + a.w * w.w;
    }
    for (int off = 32; off; off >>= 1) acc += __shfl_down(acc, off, 64);
    __shared__ float red[4];
    if ((threadIdx.x & 63) == 0) red[threadIdx.x >> 6] = acc;
    __syncthreads();
    if (threadIdx.x == 0) {
        float s = red[0] + red[1] + red[2] + red[3] + bm[0];
        out[n] = 1.f / (1.f + expf(-s));
    }
}

// ---------------- K2: A[i][o][k] stored as AT[i][k][o] ----------------
// A[i][o][s*64+t] = sum_c w_c1[o][2c+s] * f[i][c][t]
__global__ __launch_bounds__(256) void k_amat(
    const float* __restrict__ Fp, const float* __restrict__ wc1,
    float* __restrict__ AT)
{
    int i  = blockIdx.x >> 2;
    int kq = blockIdx.x & 3;          // k in [kq*32, kq*32+32)
    int o  = threadIdx.x >> 3;
    int kk = (threadIdx.x & 7) * 4;
    int s  = kq >> 1;                 // uniform in block
    int t0 = (kq & 1) * 32 + kk;
    const float* fpi  = Fp + i * 16384;
    const float* wrow = wc1 + o * 512 + s;
    float4 acc = {0.f, 0.f, 0.f, 0.f};
    #pragma unroll 4
    for (int c = 0; c < 256; ++c) {
        float wv = wrow[2 * c];
        float4 fv = *reinterpret_cast<const float4*>(fpi + c * 64 + t0);
        acc.x += wv * fv.x; acc.y += wv * fv.y;
        acc.z += wv * fv.z; acc.w += wv * fv.w;
    }
    int kbase = kq * 32 + kk;
    float* ap = AT + i * 4096 + kbase * 32 + o;
    ap[0]  = acc.x; ap[32] = acc.y;
    ap[64] = acc.z; ap[96] = acc.w;
}

// ---------------- K3: per-pair GEMM + tail ----------------
__global__ __launch_bounds__(256) void k_pairs(
    const float* __restrict__ FT, const float* __restrict__ AT,
    const float* __restrict__ b_c1, const float* __restrict__ w_c2,
    const float* __restrict__ b_c2, const float* __restrict__ w_fc1,
    const float* __restrict__ b_fc1, const float* __restrict__ w_fc2,
    const float* __restrict__ b_fc2, const float* __restrict__ w_fc3,
    const float* __restrict__ b_fc3, float* __restrict__ out)
{
    __shared__ float smem[20480];     // 80 KB: A [0,4096), B [4096,20480)
    int p = blockIdx.x;
    int i = 0, rem = p;
    while (rem >= 63 - i) { rem -= 63 - i; ++i; }
    int j = i + 1 + rem;
    int tid = threadIdx.x;

    { // stage A (1024 float4) + B (4096 float4), coalesced
        const float4* srcA = reinterpret_cast<const float4*>(AT + i * 4096);
        float4* dstA = reinterpret_cast<float4*>(smem);
        for (int u = tid; u < 1024; u += 256) dstA[u] = srcA[u];
        const float4* srcB = reinterpret_cast<const float4*>(FT + j * 16384);
        float4* dstB = reinterpret_cast<float4*>(smem + 4096);
        for (int u = tid; u < 4096; u += 256) dstB[u] = srcB[u];
    }
    __syncthreads();

    int o_t = tid >> 5, e_t = tid & 31;
    const float4* A4 = reinterpret_cast<const float4*>(smem);
    const float4* B4 = reinterpret_cast<const float4*>(smem + 4096);
    float acc[4][4] = {};
    #pragma unroll 4
    for (int k = 0; k < 128; ++k) {
        float4 av = A4[k * 8 + o_t];
        float4 bv = B4[k * 32 + e_t];
        acc[0][0] += av.x * bv.x; acc[0][1] += av.x * bv.y;
        acc[0][2] += av.x * bv.z; acc[0][3] += av.x * bv.w;
        acc[1][0] += av.y * bv.x; acc[1][1] += av.y * bv.y;
        acc[1][2] += av.y * bv.z; acc[1][3] += av.y * bv.w;
        acc[2][0] += av.z * bv.x; acc[2][1] += av.z * bv.y;
        acc[2][2] += av.z * bv.z; acc[2][3] += av.z * bv.w;
        acc[3][0] += av.w * bv.x; acc[3][1] += av.w * bv.y;
        acc[3][2] += av.w * bv.z; acc[3][3] += av.w * bv.w;
    }
    __syncthreads();   // everyone done reading A/B; reuse smem

    // H[o][e] = acc + b_c1[o]  -> smem[4096 .. 8192)
    float* H = smem + 4096;
    int o0 = o_t * 4, e0 = e_t * 4;
    #pragma unroll
    for (int a = 0; a < 4; ++a) {
        float bb = b_c1[o0 + a];
        #pragma unroll
        for (int bcol = 0; bcol < 4; ++bcol)
            H[(o0 + a) * 128 + e0 + bcol] = acc[a][bcol] + bb;
    }
    __syncthreads();

    // pool1: pooled[o][h2*2+w2] = max over e in {8h2+2w2, +1, +4, +5}
    float* PL = smem + 8192;          // 1024 floats
    for (int idx = tid; idx < 1024; idx += 256) {
        int o = idx >> 5, h2 = (idx >> 1) & 15, w2 = idx & 1;
        const float* hp = H + o * 128 + h2 * 8 + w2 * 2;
        PL[o * 32 + h2 * 2 + w2] =
            fmaxf(fmaxf(hp[0], hp[1]), fmaxf(hp[4], hp[5]));
    }
    __syncthreads();

    // conv2: c2[o2][pos] = b_c2[o2] + sum_o w_c2[o2][o]*pooled[o][pos]
    float* C2 = smem + 9216;          // 256 floats
    {
        int o2 = tid >> 5, pos = tid & 31;
        float a2 = b_c2[o2];
        #pragma unroll 8
        for (int o = 0; o < 32; ++o) a2 += w_c2[o2 * 32 + o] * PL[o * 32 + pos];
        C2[o2 * 32 + pos] = a2;
    }
    __syncthreads();

    // pool2 -> v[o2*8+h3]
    float* V = smem + 9472;           // 64 floats
    if (tid < 64) {
        int o2 = tid >> 3, h3 = tid & 7;
        const float* cp = C2 + o2 * 32 + h3 * 4;
        V[tid] = fmaxf(fmaxf(cp[0], cp[1]), fmaxf(cp[2], cp[3]));
    }
    __syncthreads();

    float* R1 = smem + 9536;          // 32
    if (tid < 32) {
        float a = b_fc1[tid];
        const float* wr = w_fc1 + tid * 64;
        #pragma unroll 8
        for (int u = 0; u < 64; ++u) a += wr[u] * V[u];
        R1[tid] = fmaxf(a, 0.f);
    }
    __syncthreads();

    float* R2 = smem + 9568;          // 8
    if (tid < 8) {
        float a = b_fc2[tid];
        #pragma unroll 8
        for (int u = 0; u < 32; ++u) a += w_fc2[tid * 32 + u] * R1[u];
        R2[tid] = fmaxf(a, 0.f);
    }
    __syncthreads();

    if (tid == 0) {
        float a = b_fc3[0];
        #pragma unroll
        for (int u = 0; u < 8; ++u) a += w_fc3[u] * R2[u];
        out[64 + p] = 1.f / (1.f + expf(-a));
    }
}

extern "C" void kernel_launch(void* const* d_in, const int* in_sizes, int n_in,
                              void* d_out, int out_size, void* d_ws, size_t ws_size,
                              hipStream_t stream) {
    const float* x        = (const float*)d_in[0];
    const float* w_conv1d = (const float*)d_in[1];
    const float* b_conv1d = (const float*)d_in[2];
    const float* w_c1     = (const float*)d_in[3];
    const float* b_c1     = (const float*)d_in[4];
    const float* w_c2     = (const float*)d_in[5];
    const float* b_c2     = (const float*)d_in[6];
    const float* w_fc1    = (const float*)d_in[7];
    const float* b_fc1    = (const float*)d_in[8];
    const float* w_fc2    = (const float*)d_in[9];
    const float* b_fc2    = (const float*)d_in[10];
    const float* w_fc3    = (const float*)d_in[11];
    const float* b_fc3    = (const float*)d_in[12];
    const float* w_mlp    = (const float*)d_in[13];
    const float* b_mlp    = (const float*)d_in[14];
    float* out = (float*)d_out;

    float* FT = (float*)d_ws;             // 64*16384 f32 = 4 MB
    float* Fp = FT + 64 * 16384;          // 4 MB
    float* AT = Fp + 64 * 16384;          // 1 MB

    hipLaunchKernelGGL(k_conv1d, dim3(1024), dim3(256), 0, stream,
                       x, w_conv1d, b_conv1d, Fp, FT);
    hipLaunchKernelGGL(k_score, dim3(64), dim3(256), 0, stream,
                       x, w_mlp, b_mlp, out);
    hipLaunchKernelGGL(k_amat, dim3(256), dim3(256), 0, stream,
                       Fp, w_c1, AT);
    hipLaunchKernelGGL(k_pairs, dim3(2016), dim3(256), 0, stream,
                       FT, AT, b_c1, w_c2, b_c2, w_fc1, b_fc1,
                       w_fc2, b_fc2, w_fc3, b_fc3, out);
}

// Round 3
// 293.526 us; speedup vs baseline: 1.0391x; 1.0391x over previous
//
#include <hip/hip_runtime.h>
#include <hip/hip_bf16.h>
#include <math.h>

// N=64 samples, C=512, T=64, P=2016 pairs
// f[n][d][t], d in [0,256):  f = w_conv1d @ x + b_conv1d
// FT[n][k][e] = f[n][(k>>6)*128 + e][k&63]          (B-operand layout, 4 MB)
// AT[i][k][o] = A[i][o][k],  A[i][o][s*64+t] = sum_c' w_c1[o][2c'+s] f[i][c'][t]
//   computed directly from x via WaT:  A[i][r][t] = sum_cin WaT[cin][r] x[i][cin][t] + Ab[r]
//   WaT[cin][r=s*32+o] = sum_c' w_c1[o][2c'+s] w_conv1d[c'][cin]
// h1[p][o][e] = sum_k A[o][k] B[k][e] + b_c1[o]
// ws layout (floats): FT 1048576 | AT 262144 | wT 131072 | WaT 32768 | Ab 64
//   total 5.63 MB  (round-1's 9.0 MB proved safe; round-2's 9.56 MB overflowed)

// ---------------- k_transpose: dst[c][r] = src[r][c] ----------------
__global__ __launch_bounds__(256) void k_transpose(
    const float* __restrict__ src, float* __restrict__ dst, int R, int C)
{
    __shared__ float tile[32][33];
    int c0 = blockIdx.x * 32, r0 = blockIdx.y * 32;
    int tx = threadIdx.x & 31, ty = threadIdx.x >> 5;   // 32 x 8
    #pragma unroll
    for (int dy = 0; dy < 32; dy += 8) {
        int r = r0 + ty + dy, c = c0 + tx;
        if (r < R && c < C) tile[ty + dy][tx] = src[r * C + c];
    }
    __syncthreads();
    #pragma unroll
    for (int dy = 0; dy < 32; dy += 8) {
        int c = c0 + ty + dy, r = r0 + tx;
        if (c < C && r < R) dst[c * R + r] = tile[tx][ty + dy];
    }
}

// ---------------- k_wa: WaT[cin][r] + Ab[r] ----------------
// grid 128 blocks: block b covers r = b>>1, cin = (b&1)*256 + tid
__global__ __launch_bounds__(256) void k_wa(
    const float* __restrict__ w_c1, const float* __restrict__ w_conv,
    const float* __restrict__ b_conv, float* __restrict__ WaT,
    float* __restrict__ Ab)
{
    int r = blockIdx.x >> 1;
    int cin = (blockIdx.x & 1) * 256 + threadIdx.x;
    int s = r >> 5, o = r & 31;
    const float* wrow = w_c1 + o * 512 + s;   // stride 2 over c'
    float acc = 0.f;
    #pragma unroll 4
    for (int c = 0; c < 256; ++c)
        acc += wrow[2 * c] * w_conv[c * 512 + cin];
    WaT[cin * 64 + r] = acc;
    if (blockIdx.x == 0 && threadIdx.x < 64) {
        int rr = threadIdx.x, ss = rr >> 5, oo = rr & 31;
        const float* wr2 = w_c1 + oo * 512 + ss;
        float a = 0.f;
        for (int c = 0; c < 256; ++c) a += wr2[2 * c] * b_conv[c];
        Ab[rr] = a;
    }
}

// ---------------- K1: conv1d -> FT (B-layout) ----------------
// grid: 512 blocks = n(64) x tg(8); thread: d = tid, t = tg*8 .. +8
__global__ __launch_bounds__(256) void k_conv1d(
    const float* __restrict__ x, const float* __restrict__ wT,
    const float* __restrict__ b, float* __restrict__ FT)
{
    int n  = blockIdx.x >> 3;
    int t0 = (blockIdx.x & 7) * 8;
    int d  = threadIdx.x;
    const float* xp = x + n * 32768 + t0;
    float acc[8] = {};
    #pragma unroll 4
    for (int c = 0; c < 512; ++c) {
        float wv = wT[c * 256 + d];                       // coalesced
        float4 xa = *reinterpret_cast<const float4*>(xp + c * 64);      // broadcast
        float4 xb = *reinterpret_cast<const float4*>(xp + c * 64 + 4);  // broadcast
        acc[0] += wv * xa.x; acc[1] += wv * xa.y;
        acc[2] += wv * xa.z; acc[3] += wv * xa.w;
        acc[4] += wv * xb.x; acc[5] += wv * xb.y;
        acc[6] += wv * xb.z; acc[7] += wv * xb.w;
    }
    float bias = b[d];
    #pragma unroll
    for (int u = 0; u < 8; ++u) acc[u] += bias;
    // B-layout: FT[n][k][e], k = (d>>7)*64 + t, e = d & 127 (coalesced in e)
    int e = d & 127, s = d >> 7;
    float* ftp = FT + n * 16384 + (s * 64 + t0) * 128 + e;
    #pragma unroll
    for (int u = 0; u < 8; ++u) ftp[u * 128] = acc[u];
}

// ---------------- K_score: per-sample sigmoid(x . w_mlp + b) ----------------
__global__ __launch_bounds__(256) void k_score(
    const float* __restrict__ x, const float* __restrict__ wm,
    const float* __restrict__ bm, float* __restrict__ out)
{
    int n = blockIdx.x;
    const float4* x4 = reinterpret_cast<const float4*>(x + n * 32768);
    const float4* w4 = reinterpret_cast<const float4*>(wm);
    float acc = 0.f;
    for (int u = threadIdx.x; u < 8192; u += 256) {
        float4 a = x4[u], w = w4[u];
        acc += a.x * w.x + a.y * w.y + a.z * w.z + a.w * w.w;
    }
    for (int off = 32; off; off >>= 1) acc += __shfl_down(acc, off, 64);
    __shared__ float red[4];
    if ((threadIdx.x & 63) == 0) red[threadIdx.x >> 6] = acc;
    __syncthreads();
    if (threadIdx.x == 0) {
        float s = red[0] + red[1] + red[2] + red[3] + bm[0];
        out[n] = 1.f / (1.f + expf(-s));
    }
}

// ---------------- K2: AT[i][k][o] from x via WaT ----------------
// grid 64 (one per i); thread: r = tid&63 (s=r>>5,o=r&31), tg = tid>>6, t = tg*16..+16
__global__ __launch_bounds__(256) void k_amat(
    const float* __restrict__ x, const float* __restrict__ WaT,
    const float* __restrict__ Ab, float* __restrict__ AT)
{
    int i = blockIdx.x;
    int r = threadIdx.x & 63, tg = threadIdx.x >> 6;
    int t0 = tg * 16;
    int s = r >> 5, o = r & 31;
    const float* xp = x + i * 32768 + t0;
    float acc[16] = {};
    #pragma unroll 4
    for (int cin = 0; cin < 512; ++cin) {
        float wv = WaT[cin * 64 + r];                     // coalesced
        float4 xa = *reinterpret_cast<const float4*>(xp + cin * 64);       // bcast
        float4 xb = *reinterpret_cast<const float4*>(xp + cin * 64 + 4);
        float4 xc = *reinterpret_cast<const float4*>(xp + cin * 64 + 8);
        float4 xd = *reinterpret_cast<const float4*>(xp + cin * 64 + 12);
        acc[0]  += wv * xa.x; acc[1]  += wv * xa.y; acc[2]  += wv * xa.z; acc[3]  += wv * xa.w;
        acc[4]  += wv * xb.x; acc[5]  += wv * xb.y; acc[6]  += wv * xb.z; acc[7]  += wv * xb.w;
        acc[8]  += wv * xc.x; acc[9]  += wv * xc.y; acc[10] += wv * xc.z; acc[11] += wv * xc.w;
        acc[12] += wv * xd.x; acc[13] += wv * xd.y; acc[14] += wv * xd.z; acc[15] += wv * xd.w;
    }
    float ab = Ab[r];
    float* ap = AT + i * 4096 + (s * 64 + t0) * 32 + o;
    #pragma unroll
    for (int u = 0; u < 16; ++u) ap[u * 32] = acc[u] + ab;
}

// ---------------- K3: per-pair GEMM + tail ----------------
__global__ __launch_bounds__(256) void k_pairs(
    const float* __restrict__ FT, const float* __restrict__ AT,
    const float* __restrict__ b_c1, const float* __restrict__ w_c2,
    const float* __restrict__ b_c2, const float* __restrict__ w_fc1,
    const float* __restrict__ b_fc1, const float* __restrict__ w_fc2,
    const float* __restrict__ b_fc2, const float* __restrict__ w_fc3,
    const float* __restrict__ b_fc3, float* __restrict__ out)
{
    __shared__ float smem[20480];     // 80 KB: A [0,4096), B [4096,20480)
    int p = blockIdx.x;
    int i = 0, rem = p;
    while (rem >= 63 - i) { rem -= 63 - i; ++i; }
    int j = i + 1 + rem;
    int tid = threadIdx.x;

    { // stage A (1024 float4) + B (4096 float4), coalesced
        const float4* srcA = reinterpret_cast<const float4*>(AT + i * 4096);
        float4* dstA = reinterpret_cast<float4*>(smem);
        for (int u = tid; u < 1024; u += 256) dstA[u] = srcA[u];
        const float4* srcB = reinterpret_cast<const float4*>(FT + j * 16384);
        float4* dstB = reinterpret_cast<float4*>(smem + 4096);
        for (int u = tid; u < 4096; u += 256) dstB[u] = srcB[u];
    }
    __syncthreads();

    int o_t = tid >> 5, e_t = tid & 31;
    const float4* A4 = reinterpret_cast<const float4*>(smem);
    const float4* B4 = reinterpret_cast<const float4*>(smem + 4096);
    float acc[4][4] = {};
    #pragma unroll 4
    for (int k = 0; k < 128; ++k) {
        float4 av = A4[k * 8 + o_t];
        float4 bv = B4[k * 32 + e_t];
        acc[0][0] += av.x * bv.x; acc[0][1] += av.x * bv.y;
        acc[0][2] += av.x * bv.z; acc[0][3] += av.x * bv.w;
        acc[1][0] += av.y * bv.x; acc[1][1] += av.y * bv.y;
        acc[1][2] += av.y * bv.z; acc[1][3] += av.y * bv.w;
        acc[2][0] += av.z * bv.x; acc[2][1] += av.z * bv.y;
        acc[2][2] += av.z * bv.z; acc[2][3] += av.z * bv.w;
        acc[3][0] += av.w * bv.x; acc[3][1] += av.w * bv.y;
        acc[3][2] += av.w * bv.z; acc[3][3] += av.w * bv.w;
    }
    __syncthreads();   // everyone done reading A/B; reuse smem

    // H[o][e] = acc + b_c1[o]  -> smem[4096 .. 8192)
    float* H = smem + 4096;
    int o0 = o_t * 4, e0 = e_t * 4;
    #pragma unroll
    for (int a = 0; a < 4; ++a) {
        float bb = b_c1[o0 + a];
        #pragma unroll
        for (int bcol = 0; bcol < 4; ++bcol)
            H[(o0 + a) * 128 + e0 + bcol] = acc[a][bcol] + bb;
    }
    __syncthreads();

    // pool1: pooled[o][h2*2+w2] = max over e in {8h2+2w2, +1, +4, +5}
    float* PL = smem + 8192;          // 1024 floats
    for (int idx = tid; idx < 1024; idx += 256) {
        int o = idx >> 5, h2 = (idx >> 1) & 15, w2 = idx & 1;
        const float* hp = H + o * 128 + h2 * 8 + w2 * 2;
        PL[o * 32 + h2 * 2 + w2] =
            fmaxf(fmaxf(hp[0], hp[1]), fmaxf(hp[4], hp[5]));
    }
    __syncthreads();

    // conv2: c2[o2][pos] = b_c2[o2] + sum_o w_c2[o2][o]*pooled[o][pos]
    float* C2 = smem + 9216;          // 256 floats
    {
        int o2 = tid >> 5, pos = tid & 31;
        float a2 = b_c2[o2];
        #pragma unroll 8
        for (int o = 0; o < 32; ++o) a2 += w_c2[o2 * 32 + o] * PL[o * 32 + pos];
        C2[o2 * 32 + pos] = a2;
    }
    __syncthreads();

    // pool2 -> v[o2*8+h3]
    float* V = smem + 9472;           // 64 floats
    if (tid < 64) {
        int o2 = tid >> 3, h3 = tid & 7;
        const float* cp = C2 + o2 * 32 + h3 * 4;
        V[tid] = fmaxf(fmaxf(cp[0], cp[1]), fmaxf(cp[2], cp[3]));
    }
    __syncthreads();

    float* R1 = smem + 9536;          // 32
    if (tid < 32) {
        float a = b_fc1[tid];
        const float* wr = w_fc1 + tid * 64;
        #pragma unroll 8
        for (int u = 0; u < 64; ++u) a += wr[u] * V[u];
        R1[tid] = fmaxf(a, 0.f);
    }
    __syncthreads();

    float* R2 = smem + 9568;          // 8
    if (tid < 8) {
        float a = b_fc2[tid];
        #pragma unroll 8
        for (int u = 0; u < 32; ++u) a += w_fc2[tid * 32 + u] * R1[u];
        R2[tid] = fmaxf(a, 0.f);
    }
    __syncthreads();

    if (tid == 0) {
        float a = b_fc3[0];
        #pragma unroll
        for (int u = 0; u < 8; ++u) a += w_fc3[u] * R2[u];
        out[64 + p] = 1.f / (1.f + expf(-a));
    }
}

extern "C" void kernel_launch(void* const* d_in, const int* in_sizes, int n_in,
                              void* d_out, int out_size, void* d_ws, size_t ws_size,
                              hipStream_t stream) {
    const float* x        = (const float*)d_in[0];
    const float* w_conv1d = (const float*)d_in[1];
    const float* b_conv1d = (const float*)d_in[2];
    const float* w_c1     = (const float*)d_in[3];
    const float* b_c1     = (const float*)d_in[4];
    const float* w_c2     = (const float*)d_in[5];
    const float* b_c2     = (const float*)d_in[6];
    const float* w_fc1    = (const float*)d_in[7];
    const float* b_fc1    = (const float*)d_in[8];
    const float* w_fc2    = (const float*)d_in[9];
    const float* b_fc2    = (const float*)d_in[10];
    const float* w_fc3    = (const float*)d_in[11];
    const float* b_fc3    = (const float*)d_in[12];
    const float* w_mlp    = (const float*)d_in[13];
    const float* b_mlp    = (const float*)d_in[14];
    float* out = (float*)d_out;

    float* FT  = (float*)d_ws;                // 1048576 f  (4 MB)
    float* AT  = FT  + 64 * 16384;            //  262144 f  (1 MB)
    float* wT  = AT  + 64 * 4096;             //  131072 f  (512 KB)
    float* WaT = wT  + 512 * 256;             //   32768 f  (128 KB)
    float* Ab  = WaT + 512 * 64;              //      64 f
    // total 5.63 MB < 9 MB proven-safe bound

    hipLaunchKernelGGL(k_transpose, dim3(16, 8), dim3(256), 0, stream,
                       w_conv1d, wT, 256, 512);
    hipLaunchKernelGGL(k_wa, dim3(128), dim3(256), 0, stream,
                       w_c1, w_conv1d, b_conv1d, WaT, Ab);
    hipLaunchKernelGGL(k_conv1d, dim3(512), dim3(256), 0, stream,
                       x, wT, b_conv1d, FT);
    hipLaunchKernelGGL(k_score, dim3(64), dim3(256), 0, stream,
                       x, w_mlp, b_mlp, out);
    hipLaunchKernelGGL(k_amat, dim3(64), dim3(256), 0, stream,
                       x, WaT, Ab, AT);
    hipLaunchKernelGGL(k_pairs, dim3(2016), dim3(256), 0, stream,
                       FT, AT, b_c1, w_c2, b_c2, w_fc1, b_fc1,
                       w_fc2, b_fc2, w_fc3, b_fc3, out);
}

// Round 4
// 199.293 us; speedup vs baseline: 1.5304x; 1.4728x over previous
//
#include <hip/hip_runtime.h>
#include <hip/hip_bf16.h>
#include <math.h>

// N=64 samples, C=512, T=64, P=2016 pairs
// f[n][d][t], d in [0,256):  f = w_conv1d @ x + b_conv1d
// FT[n][k][e] = f[n][(k>>6)*128 + e][k&63]          (B-operand layout, 4 MB)
// AT[i][k][o] = A[i][o][k],  A[i][o][s*64+t] = sum_c' w_c1[o][2c'+s] f[i][c'][t]
// h1[p][o][e] = sum_k A[o][k] B[k][e] + b_c1[o]
// ws (floats): FT 1048576 | AT 262144 | wT 131072 | wc1s 16384 | part 256
//   total ~5.57 MB (9 MB proven safe in round 1; 9.56 MB overflowed in round 2)

// ---------------- k_transpose: dst[c][r] = src[r][c] ----------------
__global__ __launch_bounds__(256) void k_transpose(
    const float* __restrict__ src, float* __restrict__ dst, int R, int C)
{
    __shared__ float tile[32][33];
    int c0 = blockIdx.x * 32, r0 = blockIdx.y * 32;
    int tx = threadIdx.x & 31, ty = threadIdx.x >> 5;   // 32 x 8
    #pragma unroll
    for (int dy = 0; dy < 32; dy += 8) {
        int r = r0 + ty + dy, c = c0 + tx;
        if (r < R && c < C) tile[ty + dy][tx] = src[r * C + c];
    }
    __syncthreads();
    #pragma unroll
    for (int dy = 0; dy < 32; dy += 8) {
        int c = c0 + ty + dy, r = r0 + tx;
        if (c < C && r < R) dst[c * R + r] = tile[tx][ty + dy];
    }
}

// ---------------- k_wc1s: wc1s[c'][r] = w_c1[r&31][2c' + (r>>5)] ----------------
__global__ __launch_bounds__(256) void k_wc1s(
    const float* __restrict__ w_c1, float* __restrict__ wc1s)
{
    int idx = blockIdx.x * 256 + threadIdx.x;   // 16384
    int cp = idx >> 6, r = idx & 63;
    wc1s[idx] = w_c1[(r & 31) * 512 + 2 * cp + (r >> 5)];
}

// ---------------- K1: conv1d -> FT (B-layout) + AT (fused A-matrix) --------
// grid: 512 blocks = n(64) x tg(8); thread: d = tid, t = tg*8 .. +8
__global__ __launch_bounds__(256) void k_conv1d(
    const float* __restrict__ x, const float* __restrict__ wT,
    const float* __restrict__ b, const float* __restrict__ wc1s,
    float* __restrict__ FT, float* __restrict__ AT)
{
    __shared__ float fs[8 * 256];      // fs[u][d] = f[d][t0+u], 8 KB
    __shared__ float wls[16384];       // wc1s copy, 64 KB  (total 72 KB)
    int n  = blockIdx.x >> 3;
    int t0 = (blockIdx.x & 7) * 8;
    int d  = threadIdx.x;

    { // stage wc1s -> LDS (coalesced float4)
        const float4* src = reinterpret_cast<const float4*>(wc1s);
        float4* dst = reinterpret_cast<float4*>(wls);
        #pragma unroll
        for (int u = 0; u < 16; ++u) dst[u * 256 + d] = src[u * 256 + d];
    }

    const float* xp = x + n * 32768 + t0;
    float acc[8] = {};
    #pragma unroll 4
    for (int c = 0; c < 512; ++c) {
        float wv = wT[c * 256 + d];                       // coalesced
        float4 xa = *reinterpret_cast<const float4*>(xp + c * 64);      // bcast
        float4 xb = *reinterpret_cast<const float4*>(xp + c * 64 + 4);  // bcast
        acc[0] += wv * xa.x; acc[1] += wv * xa.y;
        acc[2] += wv * xa.z; acc[3] += wv * xa.w;
        acc[4] += wv * xb.x; acc[5] += wv * xb.y;
        acc[6] += wv * xb.z; acc[7] += wv * xb.w;
    }
    float bias = b[d];
    #pragma unroll
    for (int u = 0; u < 8; ++u) acc[u] += bias;

    // FT[n][k][e], k = (d>>7)*64 + t, e = d & 127 (coalesced in e)
    {
        int e = d & 127, s = d >> 7;
        float* ftp = FT + n * 16384 + (s * 64 + t0) * 128 + e;
        #pragma unroll
        for (int u = 0; u < 8; ++u) ftp[u * 128] = acc[u];
    }

    // stage f tile: fs[u][d]  (lanes consecutive in d -> conflict-free)
    #pragma unroll
    for (int u = 0; u < 8; ++u) fs[u * 256 + d] = acc[u];
    __syncthreads();

    // A[r][t0+u] = sum_c' wls[c'*64+r] * fs[u][c'];  thread: r=tid&63, u=ug*2+{0,1}
    int r = d & 63, ug = d >> 6;
    const float* fs0 = fs + (ug * 2) * 256;
    const float* fs1 = fs0 + 256;
    float a0 = 0.f, a1 = 0.f;
    #pragma unroll 4
    for (int cp = 0; cp < 256; ++cp) {
        float wv = wls[cp * 64 + r];   // stride-1 over lanes: 2-way = free
        a0 += wv * fs0[cp];            // broadcast
        a1 += wv * fs1[cp];            // broadcast
    }
    int s = r >> 5, o = r & 31;
    float* ap = AT + n * 4096 + (s * 64 + t0 + ug * 2) * 32 + o;
    ap[0]  = a0;
    ap[32] = a1;
}

// ---------------- K_score part 1: partial dots ----------------
// grid (64, 4): block (n, c4) covers 8192 floats
__global__ __launch_bounds__(256) void k_score_part(
    const float* __restrict__ x, const float* __restrict__ wm,
    float* __restrict__ part)
{
    int n = blockIdx.x, c4 = blockIdx.y;
    const float4* x4 = reinterpret_cast<const float4*>(x + n * 32768) + c4 * 2048;
    const float4* w4 = reinterpret_cast<const float4*>(wm) + c4 * 2048;
    float acc = 0.f;
    for (int u = threadIdx.x; u < 2048; u += 256) {
        float4 a = x4[u], w = w4[u];
        acc += a.x * w.x + a.y * w.y + a.z * w.z + a.w * w.w;
    }
    for (int off = 32; off; off >>= 1) acc += __shfl_down(acc, off, 64);
    __shared__ float red[4];
    if ((threadIdx.x & 63) == 0) red[threadIdx.x >> 6] = acc;
    __syncthreads();
    if (threadIdx.x == 0)
        part[n * 4 + c4] = red[0] + red[1] + red[2] + red[3];
}

// ---------------- K_score part 2: sigmoid ----------------
__global__ __launch_bounds__(64) void k_sig(
    const float* __restrict__ part, const float* __restrict__ bm,
    float* __restrict__ out)
{
    int n = threadIdx.x;
    float s = part[n * 4] + part[n * 4 + 1] + part[n * 4 + 2] + part[n * 4 + 3]
            + bm[0];
    out[n] = 1.f / (1.f + expf(-s));
}

// ---------------- K3: per-pair GEMM + tail ----------------
__global__ __launch_bounds__(256) void k_pairs(
    const float* __restrict__ FT, const float* __restrict__ AT,
    const float* __restrict__ b_c1, const float* __restrict__ w_c2,
    const float* __restrict__ b_c2, const float* __restrict__ w_fc1,
    const float* __restrict__ b_fc1, const float* __restrict__ w_fc2,
    const float* __restrict__ b_fc2, const float* __restrict__ w_fc3,
    const float* __restrict__ b_fc3, float* __restrict__ out)
{
    __shared__ float smem[20480];     // 80 KB: A [0,4096), B [4096,20480)
    int p = blockIdx.x;
    int i = 0, rem = p;
    while (rem >= 63 - i) { rem -= 63 - i; ++i; }
    int j = i + 1 + rem;
    int tid = threadIdx.x;

    { // stage A (1024 float4) + B (4096 float4), coalesced
        const float4* srcA = reinterpret_cast<const float4*>(AT + i * 4096);
        float4* dstA = reinterpret_cast<float4*>(smem);
        for (int u = tid; u < 1024; u += 256) dstA[u] = srcA[u];
        const float4* srcB = reinterpret_cast<const float4*>(FT + j * 16384);
        float4* dstB = reinterpret_cast<float4*>(smem + 4096);
        for (int u = tid; u < 4096; u += 256) dstB[u] = srcB[u];
    }
    __syncthreads();

    int o_t = tid >> 5, e_t = tid & 31;
    const float4* A4 = reinterpret_cast<const float4*>(smem);
    const float4* B4 = reinterpret_cast<const float4*>(smem + 4096);
    float acc[4][4] = {};
    #pragma unroll 4
    for (int k = 0; k < 128; ++k) {
        float4 av = A4[k * 8 + o_t];
        float4 bv = B4[k * 32 + e_t];
        acc[0][0] += av.x * bv.x; acc[0][1] += av.x * bv.y;
        acc[0][2] += av.x * bv.z; acc[0][3] += av.x * bv.w;
        acc[1][0] += av.y * bv.x; acc[1][1] += av.y * bv.y;
        acc[1][2] += av.y * bv.z; acc[1][3] += av.y * bv.w;
        acc[2][0] += av.z * bv.x; acc[2][1] += av.z * bv.y;
        acc[2][2] += av.z * bv.z; acc[2][3] += av.z * bv.w;
        acc[3][0] += av.w * bv.x; acc[3][1] += av.w * bv.y;
        acc[3][2] += av.w * bv.z; acc[3][3] += av.w * bv.w;
    }
    __syncthreads();   // everyone done reading A/B; reuse smem

    // H[o][e] = acc + b_c1[o]  -> smem[4096 .. 8192)
    float* H = smem + 4096;
    int o0 = o_t * 4, e0 = e_t * 4;
    #pragma unroll
    for (int a = 0; a < 4; ++a) {
        float bb = b_c1[o0 + a];
        #pragma unroll
        for (int bcol = 0; bcol < 4; ++bcol)
            H[(o0 + a) * 128 + e0 + bcol] = acc[a][bcol] + bb;
    }
    __syncthreads();

    // pool1
    float* PL = smem + 8192;          // 1024 floats
    for (int idx = tid; idx < 1024; idx += 256) {
        int o = idx >> 5, h2 = (idx >> 1) & 15, w2 = idx & 1;
        const float* hp = H + o * 128 + h2 * 8 + w2 * 2;
        PL[o * 32 + h2 * 2 + w2] =
            fmaxf(fmaxf(hp[0], hp[1]), fmaxf(hp[4], hp[5]));
    }
    __syncthreads();

    // conv2
    float* C2 = smem + 9216;          // 256 floats
    {
        int o2 = tid >> 5, pos = tid & 31;
        float a2 = b_c2[o2];
        #pragma unroll 8
        for (int o = 0; o < 32; ++o) a2 += w_c2[o2 * 32 + o] * PL[o * 32 + pos];
        C2[o2 * 32 + pos] = a2;
    }
    __syncthreads();

    // pool2 -> v[o2*8+h3]
    float* V = smem + 9472;           // 64 floats
    if (tid < 64) {
        int o2 = tid >> 3, h3 = tid & 7;
        const float* cp = C2 + o2 * 32 + h3 * 4;
        V[tid] = fmaxf(fmaxf(cp[0], cp[1]), fmaxf(cp[2], cp[3]));
    }
    __syncthreads();

    float* R1 = smem + 9536;          // 32
    if (tid < 32) {
        float a = b_fc1[tid];
        const float* wr = w_fc1 + tid * 64;
        #pragma unroll 8
        for (int u = 0; u < 64; ++u) a += wr[u] * V[u];
        R1[tid] = fmaxf(a, 0.f);
    }
    __syncthreads();

    float* R2 = smem + 9568;          // 8
    if (tid < 8) {
        float a = b_fc2[tid];
        #pragma unroll 8
        for (int u = 0; u < 32; ++u) a += w_fc2[tid * 32 + u] * R1[u];
        R2[tid] = fmaxf(a, 0.f);
    }
    __syncthreads();

    if (tid == 0) {
        float a = b_fc3[0];
        #pragma unroll
        for (int u = 0; u < 8; ++u) a += w_fc3[u] * R2[u];
        out[64 + p] = 1.f / (1.f + expf(-a));
    }
}

extern "C" void kernel_launch(void* const* d_in, const int* in_sizes, int n_in,
                              void* d_out, int out_size, void* d_ws, size_t ws_size,
                              hipStream_t stream) {
    const float* x        = (const float*)d_in[0];
    const float* w_conv1d = (const float*)d_in[1];
    const float* b_conv1d = (const float*)d_in[2];
    const float* w_c1     = (const float*)d_in[3];
    const float* b_c1     = (const float*)d_in[4];
    const float* w_c2     = (const float*)d_in[5];
    const float* b_c2     = (const float*)d_in[6];
    const float* w_fc1    = (const float*)d_in[7];
    const float* b_fc1    = (const float*)d_in[8];
    const float* w_fc2    = (const float*)d_in[9];
    const float* b_fc2    = (const float*)d_in[10];
    const float* w_fc3    = (const float*)d_in[11];
    const float* b_fc3    = (const float*)d_in[12];
    const float* w_mlp    = (const float*)d_in[13];
    const float* b_mlp    = (const float*)d_in[14];
    float* out = (float*)d_out;

    float* FT   = (float*)d_ws;               // 1048576 f  (4 MB)
    float* AT   = FT   + 64 * 16384;          //  262144 f  (1 MB)
    float* wT   = AT   + 64 * 4096;           //  131072 f  (512 KB)
    float* wc1s = wT   + 512 * 256;           //   16384 f  (64 KB)
    float* part = wc1s + 16384;               //     256 f
    // total ~5.57 MB

    hipLaunchKernelGGL(k_transpose, dim3(16, 8), dim3(256), 0, stream,
                       w_conv1d, wT, 256, 512);
    hipLaunchKernelGGL(k_wc1s, dim3(64), dim3(256), 0, stream, w_c1, wc1s);
    hipLaunchKernelGGL(k_conv1d, dim3(512), dim3(256), 0, stream,
                       x, wT, b_conv1d, wc1s, FT, AT);
    hipLaunchKernelGGL(k_score_part, dim3(64, 4), dim3(256), 0, stream,
                       x, w_mlp, part);
    hipLaunchKernelGGL(k_sig, dim3(1), dim3(64), 0, stream, part, b_mlp, out);
    hipLaunchKernelGGL(k_pairs, dim3(2016), dim3(256), 0, stream,
                       FT, AT, b_c1, w_c2, b_c2, w_fc1, b_fc1,
                       w_fc2, b_fc2, w_fc3, b_fc3, out);
}

// Round 5
// 166.838 us; speedup vs baseline: 1.8281x; 1.1945x over previous
//
#include <hip/hip_runtime.h>
#include <hip/hip_bf16.h>
#include <math.h>

// N=64, C=512, T=64, P=2016
// f[n][d][t], d in [0,256):  f = w_conv1d @ x + b_conv1d
// Pair GEMM: h1[p][o][e] = sum_k A_i[o][k] * B_j[k][e] + b_c1[o]
//   k = s*64+t (128), e in [0,128), B_j[k][e] = f[j][s*128+e][t]
//   A_i[o][k=s*64+t] = sum_c' w_c1[o][2c'+s] f[i][c'][t]
// Storage (bf16, XOR-swizzled for conflict-free MFMA fragment reads):
//   FTTb[n]: 32 KB, value B[k][e] at byte (e*256 + k*2) ^ ((e&7)<<4)
//   ALb[i] :  8 KB, value A[o][k] at byte (o*256 + k*2) ^ ((o&7)<<4)
// ws: FTTb 2MB | ALb 512KB | wT 512KB | wc1s 64KB | part 1KB  = ~3.1 MB
//   (9 MB proven safe round 1; round-2 9.56 MB overflowed)

typedef __attribute__((ext_vector_type(8))) short short8;
typedef __attribute__((ext_vector_type(4))) float f32x4;

__device__ __forceinline__ unsigned short f2bf(float f) {
    __hip_bfloat16 h = __float2bfloat16(f);   // RNE
    return *reinterpret_cast<unsigned short*>(&h);
}

// ---------------- k_transpose: dst[c][r] = src[r][c] ----------------
__global__ __launch_bounds__(256) void k_transpose(
    const float* __restrict__ src, float* __restrict__ dst, int R, int C)
{
    __shared__ float tile[32][33];
    int c0 = blockIdx.x * 32, r0 = blockIdx.y * 32;
    int tx = threadIdx.x & 31, ty = threadIdx.x >> 5;   // 32 x 8
    #pragma unroll
    for (int dy = 0; dy < 32; dy += 8) {
        int r = r0 + ty + dy, c = c0 + tx;
        if (r < R && c < C) tile[ty + dy][tx] = src[r * C + c];
    }
    __syncthreads();
    #pragma unroll
    for (int dy = 0; dy < 32; dy += 8) {
        int c = c0 + ty + dy, r = r0 + tx;
        if (c < C && r < R) dst[c * R + r] = tile[tx][ty + dy];
    }
}

// ---------------- k_wc1s: wc1s[c'][r] = w_c1[r&31][2c' + (r>>5)] ----------------
__global__ __launch_bounds__(256) void k_wc1s(
    const float* __restrict__ w_c1, float* __restrict__ wc1s)
{
    int idx = blockIdx.x * 256 + threadIdx.x;   // 16384
    int cp = idx >> 6, r = idx & 63;
    wc1s[idx] = w_c1[(r & 31) * 512 + 2 * cp + (r >> 5)];
}

// ---------------- K1: conv1d -> FTTb (bf16 swz) + ALb (bf16 swz) ----------
// grid: 512 blocks = n(64) x tg(8); thread: d = tid, t = tg*8 .. +8
__global__ __launch_bounds__(256) void k_conv1d(
    const float* __restrict__ x, const float* __restrict__ wT,
    const float* __restrict__ b, const float* __restrict__ wc1s,
    char* __restrict__ FTTb, char* __restrict__ ALb)
{
    __shared__ float fs[8 * 256];      // fs[u][d] = f[d][t0+u], 8 KB only
    int n  = blockIdx.x >> 3;
    int t0 = (blockIdx.x & 7) * 8;
    int d  = threadIdx.x;

    const float* xp = x + n * 32768 + t0;
    float acc[8] = {};
    #pragma unroll 4
    for (int c = 0; c < 512; ++c) {
        float wv = wT[c * 256 + d];                       // coalesced
        float4 xa = *reinterpret_cast<const float4*>(xp + c * 64);      // bcast
        float4 xb = *reinterpret_cast<const float4*>(xp + c * 64 + 4);  // bcast
        acc[0] += wv * xa.x; acc[1] += wv * xa.y;
        acc[2] += wv * xa.z; acc[3] += wv * xa.w;
        acc[4] += wv * xb.x; acc[5] += wv * xb.y;
        acc[6] += wv * xb.z; acc[7] += wv * xb.w;
    }
    float bias = b[d];
    #pragma unroll
    for (int u = 0; u < 8; ++u) acc[u] += bias;

    // B-operand store: 8 consecutive k for e=d&127 -> one swizzled 16B chunk
    {
        int e = d & 127, s = d >> 7;
        int off = ((e << 8) + ((s * 64 + t0) << 1)) ^ ((e & 7) << 4);
        short8 v;
        #pragma unroll
        for (int u = 0; u < 8; ++u) v[u] = (short)f2bf(acc[u]);
        *reinterpret_cast<short8*>(FTTb + (size_t)n * 32768 + off) = v;
    }

    // stage f tile for the A-part
    #pragma unroll
    for (int u = 0; u < 8; ++u) fs[u * 256 + d] = acc[u];
    __syncthreads();

    // A[r][t0+2ug+{0,1}] = sum_c' wc1s[c'*64+r] * fs[..][c']
    int r = d & 63, ug = d >> 6;
    const float* fs0 = fs + (ug * 2) * 256;
    const float* fs1 = fs0 + 256;
    float a0 = 0.f, a1 = 0.f;
    #pragma unroll 4
    for (int cp = 0; cp < 256; ++cp) {
        float wv = wc1s[cp * 64 + r];   // coalesced 256B + 4-wave broadcast (L2)
        a0 += wv * fs0[cp];
        a1 += wv * fs1[cp];
    }
    int o = r & 31, sA = r >> 5;
    int k = sA * 64 + t0 + ug * 2;
    int offA = ((o << 8) + (k << 1)) ^ ((o & 7) << 4);
    unsigned int pk = (unsigned int)f2bf(a0) | ((unsigned int)f2bf(a1) << 16);
    *reinterpret_cast<unsigned int*>(ALb + (size_t)n * 8192 + offA) = pk;
}

// ---------------- K_score part 1: partial dots ----------------
__global__ __launch_bounds__(256) void k_score_part(
    const float* __restrict__ x, const float* __restrict__ wm,
    float* __restrict__ part)
{
    int n = blockIdx.x, c4 = blockIdx.y;
    const float4* x4 = reinterpret_cast<const float4*>(x + n * 32768) + c4 * 2048;
    const float4* w4 = reinterpret_cast<const float4*>(wm) + c4 * 2048;
    float acc = 0.f;
    for (int u = threadIdx.x; u < 2048; u += 256) {
        float4 a = x4[u], w = w4[u];
        acc += a.x * w.x + a.y * w.y + a.z * w.z + a.w * w.w;
    }
    for (int off = 32; off; off >>= 1) acc += __shfl_down(acc, off, 64);
    __shared__ float red[4];
    if ((threadIdx.x & 63) == 0) red[threadIdx.x >> 6] = acc;
    __syncthreads();
    if (threadIdx.x == 0)
        part[n * 4 + c4] = red[0] + red[1] + red[2] + red[3];
}

// ---------------- K_score part 2: sigmoid ----------------
__global__ __launch_bounds__(64) void k_sig(
    const float* __restrict__ part, const float* __restrict__ bm,
    float* __restrict__ out)
{
    int n = threadIdx.x;
    float s = part[n * 4] + part[n * 4 + 1] + part[n * 4 + 2] + part[n * 4 + 3]
            + bm[0];
    out[n] = 1.f / (1.f + expf(-s));
}

// ---------------- K3: per-pair MFMA GEMM + tail ----------------
// 4 waves; wave w owns E-tiles {2w,2w+1} x M-tiles {0,1}; 16 mfma_16x16x32_bf16
__global__ __launch_bounds__(256) void k_pairs(
    const char* __restrict__ FTTb, const char* __restrict__ ALb,
    const float* __restrict__ b_c1, const float* __restrict__ w_c2,
    const float* __restrict__ b_c2, const float* __restrict__ w_fc1,
    const float* __restrict__ b_fc1, const float* __restrict__ w_fc2,
    const float* __restrict__ b_fc2, const float* __restrict__ w_fc3,
    const float* __restrict__ b_fc3, float* __restrict__ out)
{
    __shared__ uint4 smq[2560];        // 40 KB: A bf16 [0,8K), B bf16 [8K,40K)
    char* sm = (char*)smq;
    int p = blockIdx.x;
    int i = 0, rem = p;
    while (rem >= 63 - i) { rem -= 63 - i; ++i; }
    int j = i + 1 + rem;
    int tid = threadIdx.x;

    { // linear staging (swizzle already applied in global layout)
        const uint4* sA = reinterpret_cast<const uint4*>(ALb + (size_t)i * 8192);
        uint4* dA = reinterpret_cast<uint4*>(sm);
        #pragma unroll
        for (int u = 0; u < 2; ++u) dA[tid + 256 * u] = sA[tid + 256 * u];
        const uint4* sB = reinterpret_cast<const uint4*>(FTTb + (size_t)j * 32768);
        uint4* dB = reinterpret_cast<uint4*>(sm + 8192);
        #pragma unroll
        for (int u = 0; u < 8; ++u) dB[tid + 256 * u] = sB[tid + 256 * u];
    }
    __syncthreads();

    int l = tid & 63, wid = tid >> 6;
    int col = l & 15;
    int lk16 = (l >> 4) << 4;          // byte offset of this lane's k-subchunk
    int xr = (col & 7) << 4;           // XOR swizzle (row&7 == col&7 here)
    int oa0 = col, oa1 = col + 16;
    int e0 = wid * 32 + col, e1 = e0 + 16;

    f32x4 acc00 = {0.f,0.f,0.f,0.f}, acc01 = {0.f,0.f,0.f,0.f};
    f32x4 acc10 = {0.f,0.f,0.f,0.f}, acc11 = {0.f,0.f,0.f,0.f};
    #pragma unroll
    for (int ks = 0; ks < 4; ++ks) {
        int kb = ks * 64 + lk16;
        short8 a0 = *reinterpret_cast<const short8*>(sm + (((oa0 << 8) + kb) ^ xr));
        short8 a1 = *reinterpret_cast<const short8*>(sm + (((oa1 << 8) + kb) ^ xr));
        short8 b0 = *reinterpret_cast<const short8*>(sm + 8192 + (((e0 << 8) + kb) ^ xr));
        short8 b1 = *reinterpret_cast<const short8*>(sm + 8192 + (((e1 << 8) + kb) ^ xr));
        acc00 = __builtin_amdgcn_mfma_f32_16x16x32_bf16(a0, b0, acc00, 0, 0, 0);
        acc01 = __builtin_amdgcn_mfma_f32_16x16x32_bf16(a0, b1, acc01, 0, 0, 0);
        acc10 = __builtin_amdgcn_mfma_f32_16x16x32_bf16(a1, b0, acc10, 0, 0, 0);
        acc11 = __builtin_amdgcn_mfma_f32_16x16x32_bf16(a1, b1, acc11, 0, 0, 0);
    }
    __syncthreads();   // staging no longer needed; write H over it

    // D layout: col = lane&15, row = (lane>>4)*4 + reg   [m89-verified]
    float* H = (float*)sm;             // H[32][128] f32, 16 KB
    int rowbase = (l >> 4) * 4;
    #pragma unroll
    for (int r4 = 0; r4 < 4; ++r4) {
        int o0 = rowbase + r4, o1 = o0 + 16;
        float bb0 = b_c1[o0], bb1 = b_c1[o1];
        H[o0 * 128 + e0] = acc00[r4] + bb0;
        H[o0 * 128 + e1] = acc01[r4] + bb0;
        H[o1 * 128 + e0] = acc10[r4] + bb1;
        H[o1 * 128 + e1] = acc11[r4] + bb1;
    }
    __syncthreads();

    // pool1
    float* PL = (float*)(sm + 16384);  // 1024 f
    for (int idx = tid; idx < 1024; idx += 256) {
        int o = idx >> 5, h2 = (idx >> 1) & 15, w2 = idx & 1;
        const float* hp = H + o * 128 + h2 * 8 + w2 * 2;
        PL[o * 32 + h2 * 2 + w2] =
            fmaxf(fmaxf(hp[0], hp[1]), fmaxf(hp[4], hp[5]));
    }
    __syncthreads();

    // conv2
    float* C2 = (float*)(sm + 20480);  // 256 f
    {
        int o2 = tid >> 5, pos = tid & 31;
        float a2 = b_c2[o2];
        #pragma unroll 8
        for (int o = 0; o < 32; ++o) a2 += w_c2[o2 * 32 + o] * PL[o * 32 + pos];
        C2[o2 * 32 + pos] = a2;
    }
    __syncthreads();

    // pool2
    float* V = (float*)(sm + 21504);   // 64 f
    if (tid < 64) {
        int o2 = tid >> 3, h3 = tid & 7;
        const float* cp = C2 + o2 * 32 + h3 * 4;
        V[tid] = fmaxf(fmaxf(cp[0], cp[1]), fmaxf(cp[2], cp[3]));
    }
    __syncthreads();

    float* R1 = (float*)(sm + 21760);  // 32 f
    if (tid < 32) {
        float a = b_fc1[tid];
        const float* wr = w_fc1 + tid * 64;
        #pragma unroll 8
        for (int u = 0; u < 64; ++u) a += wr[u] * V[u];
        R1[tid] = fmaxf(a, 0.f);
    }
    __syncthreads();

    float* R2 = (float*)(sm + 21888);  // 8 f
    if (tid < 8) {
        float a = b_fc2[tid];
        #pragma unroll 8
        for (int u = 0; u < 32; ++u) a += w_fc2[tid * 32 + u] * R1[u];
        R2[tid] = fmaxf(a, 0.f);
    }
    __syncthreads();

    if (tid == 0) {
        float a = b_fc3[0];
        #pragma unroll
        for (int u = 0; u < 8; ++u) a += w_fc3[u] * R2[u];
        out[64 + p] = 1.f / (1.f + expf(-a));
    }
}

extern "C" void kernel_launch(void* const* d_in, const int* in_sizes, int n_in,
                              void* d_out, int out_size, void* d_ws, size_t ws_size,
                              hipStream_t stream) {
    const float* x        = (const float*)d_in[0];
    const float* w_conv1d = (const float*)d_in[1];
    const float* b_conv1d = (const float*)d_in[2];
    const float* w_c1     = (const float*)d_in[3];
    const float* b_c1     = (const float*)d_in[4];
    const float* w_c2     = (const float*)d_in[5];
    const float* b_c2     = (const float*)d_in[6];
    const float* w_fc1    = (const float*)d_in[7];
    const float* b_fc1    = (const float*)d_in[8];
    const float* w_fc2    = (const float*)d_in[9];
    const float* b_fc2    = (const float*)d_in[10];
    const float* w_fc3    = (const float*)d_in[11];
    const float* b_fc3    = (const float*)d_in[12];
    const float* w_mlp    = (const float*)d_in[13];
    const float* b_mlp    = (const float*)d_in[14];
    float* out = (float*)d_out;

    char*  FTTb = (char*)d_ws;                   // 64*32768 = 2 MB
    char*  ALb  = FTTb + (size_t)64 * 32768;     // 64*8192  = 512 KB
    float* wT   = (float*)(ALb + (size_t)64 * 8192);  // 131072 f (512 KB)
    float* wc1s = wT + 131072;                   // 16384 f (64 KB)
    float* part = wc1s + 16384;                  // 256 f
    // total ~3.1 MB

    hipLaunchKernelGGL(k_transpose, dim3(16, 8), dim3(256), 0, stream,
                       w_conv1d, wT, 256, 512);
    hipLaunchKernelGGL(k_wc1s, dim3(64), dim3(256), 0, stream, w_c1, wc1s);
    hipLaunchKernelGGL(k_conv1d, dim3(512), dim3(256), 0, stream,
                       x, wT, b_conv1d, wc1s, FTTb, ALb);
    hipLaunchKernelGGL(k_score_part, dim3(64, 4), dim3(256), 0, stream,
                       x, w_mlp, part);
    hipLaunchKernelGGL(k_sig, dim3(1), dim3(64), 0, stream, part, b_mlp, out);
    hipLaunchKernelGGL(k_pairs, dim3(2016), dim3(256), 0, stream,
                       FTTb, ALb, b_c1, w_c2, b_c2, w_fc1, b_fc1,
                       w_fc2, b_fc2, w_fc3, b_fc3, out);
}

// Round 6
// 159.224 us; speedup vs baseline: 1.9155x; 1.0478x over previous
//
#include <hip/hip_runtime.h>
#include <hip/hip_bf16.h>
#include <math.h>

// N=64, C=512, T=64, P=2016
// G[n] = W'(320x512) @ x[n](512x64) + Gb;  rows 0..256 = f, rows 256.. = A
//   W' = [w_conv1d ; Wa],  Wa[r,cin] = sum_c' w_c1[o,2c'+s] w_conv1d[c',cin]
//   Gb = [b_conv1d ; Ab],  Ab[r]    = sum_c' w_c1[o,2c'+s] b_conv1d[c']   (r = s*32+o)
// Pair GEMM (k_pairs, m89-verified fragment conventions):
//   h1[p][o][e] = sum_k A_i[o][k] B_j[k][e] + b_c1[o],  k=s*64+t, B_j[k][e]=f[j][s*128+e][t]
// Swizzled bf16 operand stores (byte ^ ((row&7)<<4)):
//   FTTb[n]: 32 KB  value B[k][e] at byte (e*256 + k*2) ^ ((e&7)<<4)
//   ALb[i] :  8 KB  value A[o][k] at byte (o*256 + k*2) ^ ((o&7)<<4)
// ws: xxT 4MB | FTTb 2MB | ALb 512KB | Wb 320KB | Wa 128KB | Gb/Ab/part ~3KB
//   total ~6.94 MB  (9 MB proven safe round 1; 9.56 MB overflowed round 2)

typedef __attribute__((ext_vector_type(8))) short short8;
typedef __attribute__((ext_vector_type(4))) float f32x4;

__device__ __forceinline__ unsigned short f2bf(float f) {
    __hip_bfloat16 h = __float2bfloat16(f);   // RNE
    return *reinterpret_cast<unsigned short*>(&h);
}

// ---------------- k_wa: Wa[r][cin] + Ab[r] ----------------
__global__ __launch_bounds__(256) void k_wa(
    const float* __restrict__ w_c1, const float* __restrict__ w_conv,
    const float* __restrict__ b_conv, float* __restrict__ Wa,
    float* __restrict__ Ab)
{
    int r = blockIdx.x >> 1;
    int cin = (blockIdx.x & 1) * 256 + threadIdx.x;
    int s = r >> 5, o = r & 31;
    const float* wrow = w_c1 + o * 512 + s;   // stride 2 over c'
    float acc = 0.f;
    #pragma unroll 4
    for (int c = 0; c < 256; ++c)
        acc += wrow[2 * c] * w_conv[c * 512 + cin];   // coalesced over cin
    Wa[r * 512 + cin] = acc;
    if (blockIdx.x == 0 && threadIdx.x < 64) {
        int rr = threadIdx.x, ss = rr >> 5, oo = rr & 31;
        const float* wr2 = w_c1 + oo * 512 + ss;
        float a = 0.f;
        for (int c = 0; c < 256; ++c) a += wr2[2 * c] * b_conv[c];
        Ab[rr] = a;
    }
}

// ---------------- k_wprep: Wb (bf16 320x512) + Gb (fp32 320) ----------------
__global__ __launch_bounds__(256) void k_wprep(
    const float* __restrict__ w_conv1d, const float* __restrict__ Wa,
    const float* __restrict__ b_conv1d, const float* __restrict__ Ab,
    unsigned short* __restrict__ Wb, float* __restrict__ Gb)
{
    int idx = blockIdx.x * 256 + threadIdx.x;   // 40960 = 320*512/4
    int m = idx >> 7, c4 = (idx & 127) * 4;
    const float* src = (m < 256) ? (w_conv1d + m * 512 + c4)
                                 : (Wa + (m - 256) * 512 + c4);
    float4 v = *reinterpret_cast<const float4*>(src);
    ushort4 u;
    u.x = f2bf(v.x); u.y = f2bf(v.y); u.z = f2bf(v.z); u.w = f2bf(v.w);
    *reinterpret_cast<ushort4*>(Wb + m * 512 + c4) = u;
    if (blockIdx.x == 0) {
        if (threadIdx.x < 256) Gb[threadIdx.x] = b_conv1d[threadIdx.x];
        if (threadIdx.x < 64)  Gb[256 + threadIdx.x] = Ab[threadIdx.x];
    }
}

// ---------------- k_xprep: xxT[n][t][c] = bf16(x[n][c][t]) ----------------
// grid (64, 8): n, c-chunk of 64
__global__ __launch_bounds__(256) void k_xprep(
    const float* __restrict__ x, unsigned short* __restrict__ xxT)
{
    __shared__ float tile[64][65];
    int n = blockIdx.x, c0 = blockIdx.y * 64;
    int tid = threadIdx.x;
    int cl = tid >> 4, t4 = (tid & 15) * 4;
    const float* xp = x + n * 32768 + c0 * 64;
    #pragma unroll
    for (int p = 0; p < 4; ++p) {
        int c = cl + p * 16;
        float4 v = *reinterpret_cast<const float4*>(xp + c * 64 + t4);
        tile[t4 + 0][c] = v.x; tile[t4 + 1][c] = v.y;
        tile[t4 + 2][c] = v.z; tile[t4 + 3][c] = v.w;
    }
    __syncthreads();
    int tl = tid >> 4, cl4 = (tid & 15) * 4;
    #pragma unroll
    for (int p = 0; p < 4; ++p) {
        int t = tl + p * 16;
        ushort4 u;
        u.x = f2bf(tile[t][cl4 + 0]);
        u.y = f2bf(tile[t][cl4 + 1]);
        u.z = f2bf(tile[t][cl4 + 2]);
        u.w = f2bf(tile[t][cl4 + 3]);
        *reinterpret_cast<ushort4*>(xxT + n * 32768 + t * 512 + c0 + cl4) = u;
    }
}

// ---------------- k_fgemm: G = Wb @ x + Gb -> FTTb / ALb (swizzled bf16) ---
// grid (64 n, 5 mg, 4 nt); wave w: m-tile = mg*64 + w*16, t-tile = nt*16
__global__ __launch_bounds__(256) void k_fgemm(
    const unsigned short* __restrict__ Wb, const unsigned short* __restrict__ xxT,
    const float* __restrict__ Gb, unsigned short* __restrict__ FTTb,
    unsigned short* __restrict__ ALb)
{
    int n = blockIdx.x, mg = blockIdx.y, nt = blockIdx.z;
    int tid = threadIdx.x, l = tid & 63, w = tid >> 6;
    int m0 = mg * 64 + w * 16;
    int t0 = nt * 16;
    int r15 = l & 15, kg = l >> 4;
    const unsigned short* ap = Wb + (m0 + r15) * 512 + kg * 8;
    const unsigned short* bp = xxT + n * 32768 + (t0 + r15) * 512 + kg * 8;
    f32x4 acc = {0.f, 0.f, 0.f, 0.f};
    #pragma unroll
    for (int ks = 0; ks < 16; ++ks) {
        short8 a = *reinterpret_cast<const short8*>(ap + ks * 32);
        short8 b = *reinterpret_cast<const short8*>(bp + ks * 32);
        acc = __builtin_amdgcn_mfma_f32_16x16x32_bf16(a, b, acc, 0, 0, 0);
    }
    // D: col = l&15 -> t, row = (l>>4)*4 + reg -> m   [m89-verified]
    int t = t0 + r15;
    int mrow = m0 + kg * 4;
    float4 gb = *reinterpret_cast<const float4*>(Gb + mrow);
    float gbv[4] = {gb.x, gb.y, gb.z, gb.w};
    if (m0 < 256) {
        #pragma unroll
        for (int r = 0; r < 4; ++r) {
            int m = mrow + r;
            int e = m & 127, s = m >> 7, kp = s * 64 + t;
            int off = (((e << 8) + (kp << 1)) ^ ((e & 7) << 4)) >> 1;
            FTTb[n * 16384 + off] = f2bf(acc[r] + gbv[r]);
        }
    } else {
        #pragma unroll
        for (int r = 0; r < 4; ++r) {
            int m = mrow + r;
            int rr = m - 256, o = rr & 31, sA = rr >> 5, kp = sA * 64 + t;
            int off = (((o << 8) + (kp << 1)) ^ ((o & 7) << 4)) >> 1;
            ALb[n * 4096 + off] = f2bf(acc[r] + gbv[r]);
        }
    }
}

// ---------------- K_score part 1: partial dots ----------------
__global__ __launch_bounds__(256) void k_score_part(
    const float* __restrict__ x, const float* __restrict__ wm,
    float* __restrict__ part)
{
    int n = blockIdx.x, c4 = blockIdx.y;
    const float4* x4 = reinterpret_cast<const float4*>(x + n * 32768) + c4 * 2048;
    const float4* w4 = reinterpret_cast<const float4*>(wm) + c4 * 2048;
    float acc = 0.f;
    for (int u = threadIdx.x; u < 2048; u += 256) {
        float4 a = x4[u], w = w4[u];
        acc += a.x * w.x + a.y * w.y + a.z * w.z + a.w * w.w;
    }
    for (int off = 32; off; off >>= 1) acc += __shfl_down(acc, off, 64);
    __shared__ float red[4];
    if ((threadIdx.x & 63) == 0) red[threadIdx.x >> 6] = acc;
    __syncthreads();
    if (threadIdx.x == 0)
        part[n * 4 + c4] = red[0] + red[1] + red[2] + red[3];
}

// ---------------- K_score part 2: sigmoid ----------------
__global__ __launch_bounds__(64) void k_sig(
    const float* __restrict__ part, const float* __restrict__ bm,
    float* __restrict__ out)
{
    int n = threadIdx.x;
    float s = part[n * 4] + part[n * 4 + 1] + part[n * 4 + 2] + part[n * 4 + 3]
            + bm[0];
    out[n] = 1.f / (1.f + expf(-s));
}

// ---------------- K3: per-pair MFMA GEMM + tail ----------------
__global__ __launch_bounds__(256) void k_pairs(
    const char* __restrict__ FTTb, const char* __restrict__ ALb,
    const float* __restrict__ b_c1, const float* __restrict__ w_c2,
    const float* __restrict__ b_c2, const float* __restrict__ w_fc1,
    const float* __restrict__ b_fc1, const float* __restrict__ w_fc2,
    const float* __restrict__ b_fc2, const float* __restrict__ w_fc3,
    const float* __restrict__ b_fc3, float* __restrict__ out)
{
    __shared__ uint4 smq[2560];        // 40 KB: A bf16 [0,8K), B bf16 [8K,40K)
    char* sm = (char*)smq;
    int p = blockIdx.x;
    int i = 0, rem = p;
    while (rem >= 63 - i) { rem -= 63 - i; ++i; }
    int j = i + 1 + rem;
    int tid = threadIdx.x;

    { // linear staging (swizzle already applied in global layout)
        const uint4* sA = reinterpret_cast<const uint4*>(ALb + (size_t)i * 8192);
        uint4* dA = reinterpret_cast<uint4*>(sm);
        #pragma unroll
        for (int u = 0; u < 2; ++u) dA[tid + 256 * u] = sA[tid + 256 * u];
        const uint4* sB = reinterpret_cast<const uint4*>(FTTb + (size_t)j * 32768);
        uint4* dB = reinterpret_cast<uint4*>(sm + 8192);
        #pragma unroll
        for (int u = 0; u < 8; ++u) dB[tid + 256 * u] = sB[tid + 256 * u];
    }
    __syncthreads();

    int l = tid & 63, wid = tid >> 6;
    int col = l & 15;
    int lk16 = (l >> 4) << 4;          // byte offset of this lane's k-subchunk
    int xr = (col & 7) << 4;           // XOR swizzle (row&7 == col&7 here)
    int oa0 = col, oa1 = col + 16;
    int e0 = wid * 32 + col, e1 = e0 + 16;

    f32x4 acc00 = {0.f,0.f,0.f,0.f}, acc01 = {0.f,0.f,0.f,0.f};
    f32x4 acc10 = {0.f,0.f,0.f,0.f}, acc11 = {0.f,0.f,0.f,0.f};
    #pragma unroll
    for (int ks = 0; ks < 4; ++ks) {
        int kb = ks * 64 + lk16;
        short8 a0 = *reinterpret_cast<const short8*>(sm + (((oa0 << 8) + kb) ^ xr));
        short8 a1 = *reinterpret_cast<const short8*>(sm + (((oa1 << 8) + kb) ^ xr));
        short8 b0 = *reinterpret_cast<const short8*>(sm + 8192 + (((e0 << 8) + kb) ^ xr));
        short8 b1 = *reinterpret_cast<const short8*>(sm + 8192 + (((e1 << 8) + kb) ^ xr));
        acc00 = __builtin_amdgcn_mfma_f32_16x16x32_bf16(a0, b0, acc00, 0, 0, 0);
        acc01 = __builtin_amdgcn_mfma_f32_16x16x32_bf16(a0, b1, acc01, 0, 0, 0);
        acc10 = __builtin_amdgcn_mfma_f32_16x16x32_bf16(a1, b0, acc10, 0, 0, 0);
        acc11 = __builtin_amdgcn_mfma_f32_16x16x32_bf16(a1, b1, acc11, 0, 0, 0);
    }
    __syncthreads();   // staging no longer needed; write H over it

    // D layout: col = lane&15, row = (lane>>4)*4 + reg   [m89-verified]
    float* H = (float*)sm;             // H[32][128] f32, 16 KB
    int rowbase = (l >> 4) * 4;
    #pragma unroll
    for (int r4 = 0; r4 < 4; ++r4) {
        int o0 = rowbase + r4, o1 = o0 + 16;
        float bb0 = b_c1[o0], bb1 = b_c1[o1];
        H[o0 * 128 + e0] = acc00[r4] + bb0;
        H[o0 * 128 + e1] = acc01[r4] + bb0;
        H[o1 * 128 + e0] = acc10[r4] + bb1;
        H[o1 * 128 + e1] = acc11[r4] + bb1;
    }
    __syncthreads();

    // pool1
    float* PL = (float*)(sm + 16384);  // 1024 f
    for (int idx = tid; idx < 1024; idx += 256) {
        int o = idx >> 5, h2 = (idx >> 1) & 15, w2 = idx & 1;
        const float* hp = H + o * 128 + h2 * 8 + w2 * 2;
        PL[o * 32 + h2 * 2 + w2] =
            fmaxf(fmaxf(hp[0], hp[1]), fmaxf(hp[4], hp[5]));
    }
    __syncthreads();

    // conv2
    float* C2 = (float*)(sm + 20480);  // 256 f
    {
        int o2 = tid >> 5, pos = tid & 31;
        float a2 = b_c2[o2];
        #pragma unroll 8
        for (int o = 0; o < 32; ++o) a2 += w_c2[o2 * 32 + o] * PL[o * 32 + pos];
        C2[o2 * 32 + pos] = a2;
    }
    __syncthreads();

    // pool2
    float* V = (float*)(sm + 21504);   // 64 f
    if (tid < 64) {
        int o2 = tid >> 3, h3 = tid & 7;
        const float* cp = C2 + o2 * 32 + h3 * 4;
        V[tid] = fmaxf(fmaxf(cp[0], cp[1]), fmaxf(cp[2], cp[3]));
    }
    __syncthreads();

    float* R1 = (float*)(sm + 21760);  // 32 f
    if (tid < 32) {
        float a = b_fc1[tid];
        const float* wr = w_fc1 + tid * 64;
        #pragma unroll 8
        for (int u = 0; u < 64; ++u) a += wr[u] * V[u];
        R1[tid] = fmaxf(a, 0.f);
    }
    __syncthreads();

    float* R2 = (float*)(sm + 21888);  // 8 f
    if (tid < 8) {
        float a = b_fc2[tid];
        #pragma unroll 8
        for (int u = 0; u < 32; ++u) a += w_fc2[tid * 32 + u] * R1[u];
        R2[tid] = fmaxf(a, 0.f);
    }
    __syncthreads();

    if (tid == 0) {
        float a = b_fc3[0];
        #pragma unroll
        for (int u = 0; u < 8; ++u) a += w_fc3[u] * R2[u];
        out[64 + p] = 1.f / (1.f + expf(-a));
    }
}

extern "C" void kernel_launch(void* const* d_in, const int* in_sizes, int n_in,
                              void* d_out, int out_size, void* d_ws, size_t ws_size,
                              hipStream_t stream) {
    const float* x        = (const float*)d_in[0];
    const float* w_conv1d = (const float*)d_in[1];
    const float* b_conv1d = (const float*)d_in[2];
    const float* w_c1     = (const float*)d_in[3];
    const float* b_c1     = (const float*)d_in[4];
    const float* w_c2     = (const float*)d_in[5];
    const float* b_c2     = (const float*)d_in[6];
    const float* w_fc1    = (const float*)d_in[7];
    const float* b_fc1    = (const float*)d_in[8];
    const float* w_fc2    = (const float*)d_in[9];
    const float* b_fc2    = (const float*)d_in[10];
    const float* w_fc3    = (const float*)d_in[11];
    const float* b_fc3    = (const float*)d_in[12];
    const float* w_mlp    = (const float*)d_in[13];
    const float* b_mlp    = (const float*)d_in[14];
    float* out = (float*)d_out;

    char* base = (char*)d_ws;
    unsigned short* xxT  = (unsigned short*)(base);                   // 4 MB
    unsigned short* FTTb = (unsigned short*)(base + 4194304);         // 2 MB
    unsigned short* ALb  = (unsigned short*)(base + 6291456);         // 512 KB
    unsigned short* Wb   = (unsigned short*)(base + 6815744);         // 320 KB
    float*          Wa   = (float*)(base + 7143424);                  // 128 KB
    float*          Gb   = (float*)(base + 7274496);                  // 1280 B
    float*          Ab   = (float*)(base + 7275776);                  // 256 B
    float*          part = (float*)(base + 7276032);                  // 1 KB
    // total ~6.94 MB < 9 MB proven-safe

    hipLaunchKernelGGL(k_wa, dim3(128), dim3(256), 0, stream,
                       w_c1, w_conv1d, b_conv1d, Wa, Ab);
    hipLaunchKernelGGL(k_wprep, dim3(160), dim3(256), 0, stream,
                       w_conv1d, Wa, b_conv1d, Ab, Wb, Gb);
    hipLaunchKernelGGL(k_xprep, dim3(64, 8), dim3(256), 0, stream, x, xxT);
    hipLaunchKernelGGL(k_score_part, dim3(64, 4), dim3(256), 0, stream,
                       x, w_mlp, part);
    hipLaunchKernelGGL(k_fgemm, dim3(64, 5, 4), dim3(256), 0, stream,
                       Wb, xxT, Gb, FTTb, ALb);
    hipLaunchKernelGGL(k_sig, dim3(1), dim3(64), 0, stream, part, b_mlp, out);
    hipLaunchKernelGGL(k_pairs, dim3(2016), dim3(256), 0, stream,
                       (const char*)FTTb, (const char*)ALb,
                       b_c1, w_c2, b_c2, w_fc1, b_fc1,
                       w_fc2, b_fc2, w_fc3, b_fc3, out);
}

// Round 7
// 141.303 us; speedup vs baseline: 2.1585x; 1.1268x over previous
//
#include <hip/hip_runtime.h>
#include <hip/hip_bf16.h>
#include <math.h>

// N=64, C=512, T=64, P=2016
// G[n] = W'(320x512) @ x[n](512x64) + Gb;  rows 0..256 = f, rows 256.. = A
//   W' = [w_conv1d ; Wa],  Wa[r,cin] = sum_c' w_c1[o,2c'+s] w_conv1d[c',cin]
//   Gb = [b_conv1d ; Ab],  Ab[r]    = sum_c' w_c1[o,2c'+s] b_conv1d[c']   (r = s*32+o)
// Pair GEMM (k_pairs, m89-verified fragment conventions):
//   h1[p][o][e] = sum_k A_i[o][k] B_j[k][e] + b_c1[o],  k=s*64+t, B_j[k][e]=f[j][s*128+e][t]
// Swizzled bf16 operand stores (byte ^ ((row&7)<<4)):
//   FTTb[n]: 32 KB  value B[k][e] at byte (e*256 + k*2) ^ ((e&7)<<4)
//   ALb[i] :  8 KB  value A[o][k] at byte (o*256 + k*2) ^ ((o&7)<<4)
// ws: xxT 4MB | FTTb 2MB | ALb 512KB | Wb 320KB | Wpart 512KB | Gb/part ~3KB

typedef __attribute__((ext_vector_type(8))) short short8;
typedef __attribute__((ext_vector_type(4))) float f32x4;

__device__ __forceinline__ unsigned short f2bf(float f) {
    __hip_bfloat16 h = __float2bfloat16(f);   // RNE
    return *reinterpret_cast<unsigned short*>(&h);
}

// ---------------- k_wa_part: Wpart[q][r][cin], split-K over c' ----------------
// grid (128, 4): b -> (r = b>>1, cin-half = b&1), q = c'-quarter
__global__ __launch_bounds__(256) void k_wa_part(
    const float* __restrict__ w_c1, const float* __restrict__ w_conv,
    float* __restrict__ Wpart)
{
    int b = blockIdx.x, q = blockIdx.y;
    int r = b >> 1;
    int cin = (b & 1) * 256 + threadIdx.x;
    int s = r >> 5, o = r & 31;
    const float* wrow = w_c1 + o * 512 + s;       // block-uniform (scalar)
    const float* wcp  = w_conv + cin;             // coalesced over lanes
    float acc = 0.f;
    #pragma unroll 8
    for (int c = q * 64; c < q * 64 + 64; ++c)
        acc += wrow[2 * c] * wcp[c * 512];
    Wpart[(q * 64 + r) * 512 + cin] = acc;
}

// ---------------- k_wprep: Wb (bf16 320x512) + Gb (fp32 320, incl. Ab) ------
__global__ __launch_bounds__(256) void k_wprep(
    const float* __restrict__ w_conv1d, const float* __restrict__ Wpart,
    const float* __restrict__ b_conv1d, const float* __restrict__ w_c1,
    unsigned short* __restrict__ Wb, float* __restrict__ Gb)
{
    int idx = blockIdx.x * 256 + threadIdx.x;   // 40960 = 320*512/4
    int m = idx >> 7, c4 = (idx & 127) * 4;
    float4 v;
    if (m < 256) {
        v = *reinterpret_cast<const float4*>(w_conv1d + m * 512 + c4);
    } else {
        const float* p0 = Wpart + (m - 256) * 512 + c4;
        float4 a = *reinterpret_cast<const float4*>(p0);
        float4 b = *reinterpret_cast<const float4*>(p0 + 32768);
        float4 c = *reinterpret_cast<const float4*>(p0 + 65536);
        float4 d = *reinterpret_cast<const float4*>(p0 + 98304);
        v.x = a.x + b.x + c.x + d.x;
        v.y = a.y + b.y + c.y + d.y;
        v.z = a.z + b.z + c.z + d.z;
        v.w = a.w + b.w + c.w + d.w;
    }
    ushort4 u;
    u.x = f2bf(v.x); u.y = f2bf(v.y); u.z = f2bf(v.z); u.w = f2bf(v.w);
    *reinterpret_cast<ushort4*>(Wb + m * 512 + c4) = u;

    if (blockIdx.x == 0) {
        __shared__ float abred[256];
        Gb[threadIdx.x] = b_conv1d[threadIdx.x];
        int r = threadIdx.x & 63, q = threadIdx.x >> 6;
        int s = r >> 5, o = r & 31;
        const float* wr2 = w_c1 + o * 512 + s;
        float a = 0.f;
        #pragma unroll 8
        for (int c = q * 64; c < q * 64 + 64; ++c)
            a += wr2[2 * c] * b_conv1d[c];
        abred[threadIdx.x] = a;
        __syncthreads();
        if (threadIdx.x < 64)
            Gb[256 + threadIdx.x] = abred[threadIdx.x] + abred[threadIdx.x + 64]
                                  + abred[threadIdx.x + 128] + abred[threadIdx.x + 192];
    }
}

// ---------------- k_xprep: xxT[n][t][c] = bf16(x[n][c][t]) ----------------
// grid (64, 8): n, c-chunk of 64
__global__ __launch_bounds__(256) void k_xprep(
    const float* __restrict__ x, unsigned short* __restrict__ xxT)
{
    __shared__ float tile[64][65];
    int n = blockIdx.x, c0 = blockIdx.y * 64;
    int tid = threadIdx.x;
    int cl = tid >> 4, t4 = (tid & 15) * 4;
    const float* xp = x + n * 32768 + c0 * 64;
    #pragma unroll
    for (int p = 0; p < 4; ++p) {
        int c = cl + p * 16;
        float4 v = *reinterpret_cast<const float4*>(xp + c * 64 + t4);
        tile[t4 + 0][c] = v.x; tile[t4 + 1][c] = v.y;
        tile[t4 + 2][c] = v.z; tile[t4 + 3][c] = v.w;
    }
    __syncthreads();
    int tl = tid >> 4, cl4 = (tid & 15) * 4;
    #pragma unroll
    for (int p = 0; p < 4; ++p) {
        int t = tl + p * 16;
        ushort4 u;
        u.x = f2bf(tile[t][cl4 + 0]);
        u.y = f2bf(tile[t][cl4 + 1]);
        u.z = f2bf(tile[t][cl4 + 2]);
        u.w = f2bf(tile[t][cl4 + 3]);
        *reinterpret_cast<ushort4*>(xxT + n * 32768 + t * 512 + c0 + cl4) = u;
    }
}

// ---------------- k_fgemm: G = Wb @ x + Gb -> FTTb / ALb (swizzled bf16) ---
// grid (64 n, 5 mg, 4 nt); wave w: m-tile = mg*64 + w*16, t-tile = nt*16
__global__ __launch_bounds__(256) void k_fgemm(
    const unsigned short* __restrict__ Wb, const unsigned short* __restrict__ xxT,
    const float* __restrict__ Gb, unsigned short* __restrict__ FTTb,
    unsigned short* __restrict__ ALb)
{
    int n = blockIdx.x, mg = blockIdx.y, nt = blockIdx.z;
    int tid = threadIdx.x, l = tid & 63, w = tid >> 6;
    int m0 = mg * 64 + w * 16;
    int t0 = nt * 16;
    int r15 = l & 15, kg = l >> 4;
    const unsigned short* ap = Wb + (m0 + r15) * 512 + kg * 8;
    const unsigned short* bp = xxT + n * 32768 + (t0 + r15) * 512 + kg * 8;
    f32x4 acc = {0.f, 0.f, 0.f, 0.f};
    #pragma unroll
    for (int ks = 0; ks < 16; ++ks) {
        short8 a = *reinterpret_cast<const short8*>(ap + ks * 32);
        short8 b = *reinterpret_cast<const short8*>(bp + ks * 32);
        acc = __builtin_amdgcn_mfma_f32_16x16x32_bf16(a, b, acc, 0, 0, 0);
    }
    // D: col = l&15 -> t, row = (l>>4)*4 + reg -> m   [m89-verified]
    int t = t0 + r15;
    int mrow = m0 + kg * 4;
    float4 gb = *reinterpret_cast<const float4*>(Gb + mrow);
    float gbv[4] = {gb.x, gb.y, gb.z, gb.w};
    if (m0 < 256) {
        #pragma unroll
        for (int r = 0; r < 4; ++r) {
            int m = mrow + r;
            int e = m & 127, s = m >> 7, kp = s * 64 + t;
            int off = (((e << 8) + (kp << 1)) ^ ((e & 7) << 4)) >> 1;
            FTTb[n * 16384 + off] = f2bf(acc[r] + gbv[r]);
        }
    } else {
        #pragma unroll
        for (int r = 0; r < 4; ++r) {
            int m = mrow + r;
            int rr = m - 256, o = rr & 31, sA = rr >> 5, kp = sA * 64 + t;
            int off = (((o << 8) + (kp << 1)) ^ ((o & 7) << 4)) >> 1;
            ALb[n * 4096 + off] = f2bf(acc[r] + gbv[r]);
        }
    }
}

// ---------------- K_score part 1: partial dots ----------------
__global__ __launch_bounds__(256) void k_score_part(
    const float* __restrict__ x, const float* __restrict__ wm,
    float* __restrict__ part)
{
    int n = blockIdx.x, c4 = blockIdx.y;
    const float4* x4 = reinterpret_cast<const float4*>(x + n * 32768) + c4 * 2048;
    const float4* w4 = reinterpret_cast<const float4*>(wm) + c4 * 2048;
    float acc = 0.f;
    for (int u = threadIdx.x; u < 2048; u += 256) {
        float4 a = x4[u], w = w4[u];
        acc += a.x * w.x + a.y * w.y + a.z * w.z + a.w * w.w;
    }
    for (int off = 32; off; off >>= 1) acc += __shfl_down(acc, off, 64);
    __shared__ float red[4];
    if ((threadIdx.x & 63) == 0) red[threadIdx.x >> 6] = acc;
    __syncthreads();
    if (threadIdx.x == 0)
        part[n * 4 + c4] = red[0] + red[1] + red[2] + red[3];
}

// ---------------- K3: per-pair MFMA GEMM + tail (+ fused score sigmoid) -----
__global__ __launch_bounds__(256) void k_pairs(
    const char* __restrict__ FTTb, const char* __restrict__ ALb,
    const float* __restrict__ b_c1, const float* __restrict__ w_c2,
    const float* __restrict__ b_c2, const float* __restrict__ w_fc1,
    const float* __restrict__ b_fc1, const float* __restrict__ w_fc2,
    const float* __restrict__ b_fc2, const float* __restrict__ w_fc3,
    const float* __restrict__ b_fc3, const float* __restrict__ part,
    const float* __restrict__ bm, float* __restrict__ out)
{
    __shared__ uint4 smq[2560];        // 40 KB: A bf16 [0,8K), B bf16 [8K,40K)
    char* sm = (char*)smq;
    int p = blockIdx.x;
    int i = 0, rem = p;
    while (rem >= 63 - i) { rem -= 63 - i; ++i; }
    int j = i + 1 + rem;
    int tid = threadIdx.x;

    // fused score head (was k_sig): block 0, lanes 128..191, pre-barrier
    if (p == 0 && tid >= 128 && tid < 192) {
        int n = tid - 128;
        float s = part[n * 4] + part[n * 4 + 1] + part[n * 4 + 2]
                + part[n * 4 + 3] + bm[0];
        out[n] = 1.f / (1.f + expf(-s));
    }

    { // linear staging (swizzle already applied in global layout)
        const uint4* sA = reinterpret_cast<const uint4*>(ALb + (size_t)i * 8192);
        uint4* dA = reinterpret_cast<uint4*>(sm);
        #pragma unroll
        for (int u = 0; u < 2; ++u) dA[tid + 256 * u] = sA[tid + 256 * u];
        const uint4* sB = reinterpret_cast<const uint4*>(FTTb + (size_t)j * 32768);
        uint4* dB = reinterpret_cast<uint4*>(sm + 8192);
        #pragma unroll
        for (int u = 0; u < 8; ++u) dB[tid + 256 * u] = sB[tid + 256 * u];
    }
    __syncthreads();

    int l = tid & 63, wid = tid >> 6;
    int col = l & 15;
    int lk16 = (l >> 4) << 4;          // byte offset of this lane's k-subchunk
    int xr = (col & 7) << 4;           // XOR swizzle (row&7 == col&7 here)
    int oa0 = col, oa1 = col + 16;
    int e0 = wid * 32 + col, e1 = e0 + 16;

    f32x4 acc00 = {0.f,0.f,0.f,0.f}, acc01 = {0.f,0.f,0.f,0.f};
    f32x4 acc10 = {0.f,0.f,0.f,0.f}, acc11 = {0.f,0.f,0.f,0.f};
    #pragma unroll
    for (int ks = 0; ks < 4; ++ks) {
        int kb = ks * 64 + lk16;
        short8 a0 = *reinterpret_cast<const short8*>(sm + (((oa0 << 8) + kb) ^ xr));
        short8 a1 = *reinterpret_cast<const short8*>(sm + (((oa1 << 8) + kb) ^ xr));
        short8 b0 = *reinterpret_cast<const short8*>(sm + 8192 + (((e0 << 8) + kb) ^ xr));
        short8 b1 = *reinterpret_cast<const short8*>(sm + 8192 + (((e1 << 8) + kb) ^ xr));
        acc00 = __builtin_amdgcn_mfma_f32_16x16x32_bf16(a0, b0, acc00, 0, 0, 0);
        acc01 = __builtin_amdgcn_mfma_f32_16x16x32_bf16(a0, b1, acc01, 0, 0, 0);
        acc10 = __builtin_amdgcn_mfma_f32_16x16x32_bf16(a1, b0, acc10, 0, 0, 0);
        acc11 = __builtin_amdgcn_mfma_f32_16x16x32_bf16(a1, b1, acc11, 0, 0, 0);
    }
    __syncthreads();   // staging no longer needed; write H over it

    // D layout: col = lane&15, row = (lane>>4)*4 + reg   [m89-verified]
    float* H = (float*)sm;             // H[32][128] f32, 16 KB
    int rowbase = (l >> 4) * 4;
    #pragma unroll
    for (int r4 = 0; r4 < 4; ++r4) {
        int o0 = rowbase + r4, o1 = o0 + 16;
        float bb0 = b_c1[o0], bb1 = b_c1[o1];
        H[o0 * 128 + e0] = acc00[r4] + bb0;
        H[o0 * 128 + e1] = acc01[r4] + bb0;
        H[o1 * 128 + e0] = acc10[r4] + bb1;
        H[o1 * 128 + e1] = acc11[r4] + bb1;
    }
    __syncthreads();

    // pool1
    float* PL = (float*)(sm + 16384);  // 1024 f
    for (int idx = tid; idx < 1024; idx += 256) {
        int o = idx >> 5, h2 = (idx >> 1) & 15, w2 = idx & 1;
        const float* hp = H + o * 128 + h2 * 8 + w2 * 2;
        PL[o * 32 + h2 * 2 + w2] =
            fmaxf(fmaxf(hp[0], hp[1]), fmaxf(hp[4], hp[5]));
    }
    __syncthreads();

    // conv2
    float* C2 = (float*)(sm + 20480);  // 256 f
    {
        int o2 = tid >> 5, pos = tid & 31;
        float a2 = b_c2[o2];
        #pragma unroll 8
        for (int o = 0; o < 32; ++o) a2 += w_c2[o2 * 32 + o] * PL[o * 32 + pos];
        C2[o2 * 32 + pos] = a2;
    }
    __syncthreads();

    // pool2
    float* V = (float*)(sm + 21504);   // 64 f
    if (tid < 64) {
        int o2 = tid >> 3, h3 = tid & 7;
        const float* cp = C2 + o2 * 32 + h3 * 4;
        V[tid] = fmaxf(fmaxf(cp[0], cp[1]), fmaxf(cp[2], cp[3]));
    }
    __syncthreads();

    float* R1 = (float*)(sm + 21760);  // 32 f
    if (tid < 32) {
        float a = b_fc1[tid];
        const float* wr = w_fc1 + tid * 64;
        #pragma unroll 8
        for (int u = 0; u < 64; ++u) a += wr[u] * V[u];
        R1[tid] = fmaxf(a, 0.f);
    }
    __syncthreads();

    float* R2 = (float*)(sm + 21888);  // 8 f
    if (tid < 8) {
        float a = b_fc2[tid];
        #pragma unroll 8
        for (int u = 0; u < 32; ++u) a += w_fc2[tid * 32 + u] * R1[u];
        R2[tid] = fmaxf(a, 0.f);
    }
    __syncthreads();

    if (tid == 0) {
        float a = b_fc3[0];
        #pragma unroll
        for (int u = 0; u < 8; ++u) a += w_fc3[u] * R2[u];
        out[64 + p] = 1.f / (1.f + expf(-a));
    }
}

extern "C" void kernel_launch(void* const* d_in, const int* in_sizes, int n_in,
                              void* d_out, int out_size, void* d_ws, size_t ws_size,
                              hipStream_t stream) {
    const float* x        = (const float*)d_in[0];
    const float* w_conv1d = (const float*)d_in[1];
    const float* b_conv1d = (const float*)d_in[2];
    const float* w_c1     = (const float*)d_in[3];
    const float* b_c1     = (const float*)d_in[4];
    const float* w_c2     = (const float*)d_in[5];
    const float* b_c2     = (const float*)d_in[6];
    const float* w_fc1    = (const float*)d_in[7];
    const float* b_fc1    = (const float*)d_in[8];
    const float* w_fc2    = (const float*)d_in[9];
    const float* b_fc2    = (const float*)d_in[10];
    const float* w_fc3    = (const float*)d_in[11];
    const float* b_fc3    = (const float*)d_in[12];
    const float* w_mlp    = (const float*)d_in[13];
    const float* b_mlp    = (const float*)d_in[14];
    float* out = (float*)d_out;

    char* base = (char*)d_ws;
    unsigned short* xxT   = (unsigned short*)(base);                  // 4 MB
    unsigned short* FTTb  = (unsigned short*)(base + 4194304);        // 2 MB
    unsigned short* ALb   = (unsigned short*)(base + 6291456);        // 512 KB
    unsigned short* Wb    = (unsigned short*)(base + 6815744);        // 320 KB
    float*          Wpart = (float*)(base + 7143424);                 // 512 KB
    float*          Gb    = (float*)(base + 7667712);                 // 1280 B
    float*          part  = (float*)(base + 7669760);                 // 1 KB
    // total ~7.3 MB

    hipLaunchKernelGGL(k_wa_part, dim3(128, 4), dim3(256), 0, stream,
                       w_c1, w_conv1d, Wpart);
    hipLaunchKernelGGL(k_wprep, dim3(160), dim3(256), 0, stream,
                       w_conv1d, Wpart, b_conv1d, w_c1, Wb, Gb);
    hipLaunchKernelGGL(k_xprep, dim3(64, 8), dim3(256), 0, stream, x, xxT);
    hipLaunchKernelGGL(k_score_part, dim3(64, 4), dim3(256), 0, stream,
                       x, w_mlp, part);
    hipLaunchKernelGGL(k_fgemm, dim3(64, 5, 4), dim3(256), 0, stream,
                       Wb, xxT, Gb, FTTb, ALb);
    hipLaunchKernelGGL(k_pairs, dim3(2016), dim3(256), 0, stream,
                       (const char*)FTTb, (const char*)ALb,
                       b_c1, w_c2, b_c2, w_fc1, b_fc1,
                       w_fc2, b_fc2, w_fc3, b_fc3, part, b_mlp, out);
}